// Round 8
// baseline (191.956 us; speedup 1.0000x reference)
//
#include <hip/hip_runtime.h>

// ============================================================================
// QuantumHeadAmplitude: 256 x 16-qubit statevector sim, 2 StronglyEntangling
// layers, Z-expvals, linear head.
//
// Algebra (validated R1, absmax 0.0): CNOTs are GF(2)-linear index maps,
// virtualized. stored[x] = psi_true[A^{-1} x]. A layer-1 Rot on wire w becomes
// a generalized 1q gate with XOR mask col_w(A) and role row row_w(A^{-1}).
// Expvals use final A^{-1} rows as parity masks. Normalization deferred.
//
// R2 structure (frozen): 3 passes, each = load -> register-resident gate
// stages (32 amps/thread = 5 reg bits) -> LDS bit-exchange transposes
// (fp16-packed AoS, XOR-hash banks) -> store. Inter-pass state fp16.
//
// R9 (validated, 190.4us): R6 SoA-v2f structure with f16 elements
// (Vr[16]/Vi[16] h2 pairs, lane = one stage reg bit, branch invariants
// static_asserted).
//
// R10: force v_pk_fma_f16/v_pk_mul_f16 via inline asm. R9's VALU arithmetic
// shows __builtin_elementwise_fma on h2 was SCALARIZED to 2x v_fma_f16
// (VALU-issue 33.6us == scalar model; pk model predicts 22us). Packed f16
// is the only VALU op beating the f32 floor (2x MACs at full 2cy rate).
// swap folded via op_sel:[0,1,0] op_sel_hi:[1,0,1] on src1; negation via
// neg_lo/neg_hi:[1,0,0] on src0. Same chains as R9 -> bit-identical.
// No AGPR risk: 44 VGPRs total (R3's asm failure was 64-float state).
// ============================================================================

#define BATCH 256
#define NCLS 10

typedef _Float16 h2 __attribute__((ext_vector_type(2)));
typedef float v2f __attribute__((ext_vector_type(2)));

#define KATTR __launch_bounds__(256, 4)

struct CircuitMeta { unsigned l1mask[16]; unsigned l1role[16]; unsigned fin[16]; };

__host__ __device__ constexpr CircuitMeta make_meta() {
  CircuitMeta m{};
  unsigned col[16] = {}, inv[16] = {};
  for (int w = 0; w < 16; ++w) { col[w] = 1u << (15 - w); inv[w] = 1u << (15 - w); }
  for (int w = 0; w < 16; ++w) { int c = w, t = (w + 1) & 15; col[c] ^= col[t]; inv[t] ^= inv[c]; }
  for (int w = 0; w < 16; ++w) { m.l1mask[w] = col[w]; m.l1role[w] = inv[w]; }
  for (int w = 0; w < 16; ++w) { int c = w, t = (w + 2) & 15; col[c] ^= col[t]; inv[t] ^= inv[c]; }
  for (int w = 0; w < 16; ++w) m.fin[w] = inv[w];
  return m;
}
constexpr CircuitMeta META = make_meta();

// XOR-hash for LDS bank spread (GF2-linear: HASH(a^b)=HASH(a)^HASH(b))
__host__ __device__ constexpr unsigned HASH(unsigned i) {
  return i ^ ((i >> 4) & 15u) ^ ((i >> 8) & 15u);
}

// ---- forced VOP3P packed-f16 math ------------------------------------------
__device__ __forceinline__ h2 pkmul(h2 a, h2 b) {
  h2 d; asm("v_pk_mul_f16 %0, %1, %2" : "=v"(d) : "v"(a), "v"(b)); return d;
}
__device__ __forceinline__ h2 pkfma(h2 a, h2 b, h2 c) {          // a*b + c
  h2 d; asm("v_pk_fma_f16 %0, %1, %2, %3" : "=v"(d) : "v"(a), "v"(b), "v"(c));
  return d;
}
__device__ __forceinline__ h2 pkfma_n(h2 a, h2 b, h2 c) {        // (-a)*b + c
  h2 d; asm("v_pk_fma_f16 %0, %1, %2, %3 neg_lo:[1,0,0] neg_hi:[1,0,0]"
            : "=v"(d) : "v"(a), "v"(b), "v"(c));
  return d;
}
__device__ __forceinline__ h2 pkfma_s(h2 a, h2 b, h2 c) {        // a*swap(b) + c
  h2 d; asm("v_pk_fma_f16 %0, %1, %2, %3 op_sel:[0,1,0] op_sel_hi:[1,0,1]"
            : "=v"(d) : "v"(a), "v"(b), "v"(c));
  return d;
}
__device__ __forceinline__ h2 pkfma_ns(h2 a, h2 b, h2 c) {       // (-a)*swap(b)+c
  h2 d; asm("v_pk_fma_f16 %0, %1, %2, %3 op_sel:[0,1,0] op_sel_hi:[1,0,1] "
            "neg_lo:[1,0,0] neg_hi:[1,0,0]"
            : "=v"(d) : "v"(a), "v"(b), "v"(c));
  return d;
}

__device__ __forceinline__ v2f vfma(v2f a, v2f b, v2f c) {
  return __builtin_elementwise_fma(a, b, c);
}
__device__ __forceinline__ unsigned U32(h2 a) { return __builtin_bit_cast(unsigned, a); }
__device__ __forceinline__ h2 H2(unsigned u) { return __builtin_bit_cast(h2, u); }
// AoS amp (re,im) of packed lane l (l is unroll-constant)
__device__ __forceinline__ unsigned AMPU(h2 r, h2 i, int l) {
  h2 a = l ? (h2){r.y, i.y} : (h2){r.x, i.x};
  return U32(a);
}

// E(q)_pos with pos: 0=00,1=01,2=10,3=11 ; q=1 applies XUX (00<->11, 01<->10).
__device__ __forceinline__ float esel(int q, int pos, float e00, float e01,
                                      float e10, float e11) {
  int p = q ? 3 - pos : pos;
  return p == 0 ? e00 : p == 1 ? e01 : p == 2 ? e10 : e11;
}

// ---------------------------------------------------------------------------
// Generalized 1q gate on persistent h2 SoA state. KB0..KB3 = global bits of
// the 4 k-index bits, LB = global bit of the packed lane. MG = XOR mask
// (covered by {KB*,LB}), RG = role row. tp = thread's non-reg bits (global).
// Element role parity q = parity(RG&tp) [in E via s] ^ parity(rk&k) ^ rl*l.
// Uniform rule: new[x] = ER(q,0)*x + ER(q,1)*partner.   (validated R6/R9)
// ---------------------------------------------------------------------------
template<int KB0,int KB1,int KB2,int KB3,int LB, unsigned MG, unsigned RG>
__device__ __forceinline__ void gateV(h2 (&Vr)[16], h2 (&Vi)[16],
                                      const float* __restrict__ g,
                                      int gi, unsigned tp) {
  constexpr unsigned cover = (1u<<KB0)|(1u<<KB1)|(1u<<KB2)|(1u<<KB3)|(1u<<LB);
  static_assert((MG & ~cover) == 0u, "gate mask not covered by stage reg bits");
  constexpr unsigned mk = ((MG>>KB0)&1u) | (((MG>>KB1)&1u)<<1)
                        | (((MG>>KB2)&1u)<<2) | (((MG>>KB3)&1u)<<3);
  constexpr int ml = (int)((MG>>LB)&1u);
  constexpr unsigned rk = ((RG>>KB0)&1u) | (((RG>>KB1)&1u)<<1)
                        | (((RG>>KB2)&1u)<<2) | (((RG>>KB3)&1u)<<3);
  constexpr int rl = (int)((RG>>LB)&1u);
  static_assert(mk != 0u || ml != 0, "empty mask");

  float u00r = g[gi*8+0], u00i = g[gi*8+1], u01r = g[gi*8+2], u01i = g[gi*8+3];
  float u10r = g[gi*8+4], u10i = g[gi*8+5], u11r = g[gi*8+6], u11i = g[gi*8+7];
  const bool s = (__popc(RG & tp) & 1) != 0;   // thread-part role parity
  float e00r = s?u11r:u00r, e00i = s?u11i:u00i;
  float e01r = s?u10r:u01r, e01i = s?u10i:u01i;
  float e10r = s?u01r:u10r, e10i = s?u01i:u10i;
  float e11r = s?u00r:u11r, e11i = s?u00i:u11i;
  #define ER(q,pos) (_Float16)esel((q),(pos),e00r,e01r,e10r,e11r)
  #define EI(q,pos) (_Float16)esel((q),(pos),e00i,e01i,e10i,e11i)

  if constexpr (ml == 0) {
    // -------- packed gate: butterfly across h2 regs, lanes aligned ---------
    static_assert((__builtin_popcount(rk & mk) & 1) == 1, "pair parity invariant");
    h2 c00r = {ER(0,0), ER(rl,0)}, c00i = {EI(0,0), EI(rl,0)};
    h2 c01r = {ER(0,1), ER(rl,1)}, c01i = {EI(0,1), EI(rl,1)};
    h2 c10r = {ER(0,2), ER(rl,2)}, c10i = {EI(0,2), EI(rl,2)};
    h2 c11r = {ER(0,3), ER(rl,3)}, c11i = {EI(0,3), EI(rl,3)};
    constexpr unsigned pivot = mk & (0u - mk);
    #pragma unroll
    for (int k0 = 0; k0 < 16; ++k0) {
      if (k0 & (int)pivot) continue;
      const int k1 = k0 ^ (int)mk;
      const bool podd = (__builtin_popcount(rk & (unsigned)k0) & 1) != 0; // folds
      const h2 A0r = podd?c11r:c00r, A0i = podd?c11i:c00i;  // out0 <- v0
      const h2 A1r = podd?c10r:c01r, A1i = podd?c10i:c01i;  // out0 <- v1
      const h2 B0r = podd?c01r:c10r, B0i = podd?c01i:c10i;  // out1 <- v0
      const h2 B1r = podd?c00r:c11r, B1i = podd?c00i:c11i;  // out1 <- v1
      const h2 v0r = Vr[k0], v0i = Vi[k0], v1r = Vr[k1], v1i = Vi[k1];
      h2 n0r = pkmul(A0r, v0r); n0r = pkfma_n(A0i, v0i, n0r);
      n0r = pkfma(A1r, v1r, n0r); n0r = pkfma_n(A1i, v1i, n0r);
      h2 n0i = pkmul(A0r, v0i); n0i = pkfma(A0i, v0r, n0i);
      n0i = pkfma(A1r, v1i, n0i); n0i = pkfma(A1i, v1r, n0i);
      h2 n1r = pkmul(B0r, v0r); n1r = pkfma_n(B0i, v0i, n1r);
      n1r = pkfma(B1r, v1r, n1r); n1r = pkfma_n(B1i, v1i, n1r);
      h2 n1i = pkmul(B0r, v0i); n1i = pkfma(B0i, v0r, n1i);
      n1i = pkfma(B1r, v1i, n1i); n1i = pkfma(B1i, v1r, n1i);
      Vr[k0] = n0r; Vi[k0] = n0i; Vr[k1] = n1r; Vi[k1] = n1i;
    }
  } else if constexpr (mk == 0u) {
    // -------- lane-only gate: 2x2 matvec inside each h2 (swap via op_sel) --
    static_assert(rl == 1, "lane-only gate requires rl==1");
    h2 CA0r = {ER(0,0), ER(1,0)}, CA0i = {EI(0,0), EI(1,0)};
    h2 CB0r = {ER(0,1), ER(1,1)}, CB0i = {EI(0,1), EI(1,1)};
    h2 CA1r = {ER(1,0), ER(0,0)}, CA1i = {EI(1,0), EI(0,0)};
    h2 CB1r = {ER(1,1), ER(0,1)}, CB1i = {EI(1,1), EI(0,1)};
    #pragma unroll
    for (int k = 0; k < 16; ++k) {
      const bool q = (__builtin_popcount(rk & (unsigned)k) & 1) != 0; // folds
      const h2 CAr = q?CA1r:CA0r, CAi = q?CA1i:CA0i;
      const h2 CBr = q?CB1r:CB0r, CBi = q?CB1i:CB0i;
      const h2 vr = Vr[k], vi = Vi[k];
      h2 nr = pkmul(CAr, vr); nr = pkfma_n(CAi, vi, nr);
      nr = pkfma_s(CBr, vr, nr); nr = pkfma_ns(CBi, vi, nr);
      h2 ni = pkmul(CAr, vi); ni = pkfma(CAi, vr, ni);
      ni = pkfma_s(CBr, vi, ni); ni = pkfma_s(CBi, vr, ni);
      Vr[k] = nr; Vi[k] = ni;
    }
  } else {
    // -------- cross gate: mask = lane + k bits (swap via op_sel) ----------
    constexpr int dm = __builtin_popcount(rk & mk) & 1;
    static_assert((dm ^ rl) == 1, "cross gate pair parity invariant");
    h2 CA0r = {ER(0,0), ER(rl,0)},          CA0i = {EI(0,0), EI(rl,0)};
    h2 CB0r = {ER(0,1), ER(rl,1)},          CB0i = {EI(0,1), EI(rl,1)};
    h2 CC0r = {ER(dm,0), ER(dm^rl,0)},      CC0i = {EI(dm,0), EI(dm^rl,0)};
    h2 CD0r = {ER(dm,1), ER(dm^rl,1)},      CD0i = {EI(dm,1), EI(dm^rl,1)};
    h2 CA1r = {ER(1,0), ER(1^rl,0)},        CA1i = {EI(1,0), EI(1^rl,0)};
    h2 CB1r = {ER(1,1), ER(1^rl,1)},        CB1i = {EI(1,1), EI(1^rl,1)};
    h2 CC1r = {ER(1^dm,0), ER(1^dm^rl,0)},  CC1i = {EI(1^dm,0), EI(1^dm^rl,0)};
    h2 CD1r = {ER(1^dm,1), ER(1^dm^rl,1)},  CD1i = {EI(1^dm,1), EI(1^dm^rl,1)};
    constexpr unsigned pivot = mk & (0u - mk);
    #pragma unroll
    for (int k0 = 0; k0 < 16; ++k0) {
      if (k0 & (int)pivot) continue;
      const int k1 = k0 ^ (int)mk;
      const bool q = (__builtin_popcount(rk & (unsigned)k0) & 1) != 0; // folds
      const h2 CAr = q?CA1r:CA0r, CAi = q?CA1i:CA0i;
      const h2 CBr = q?CB1r:CB0r, CBi = q?CB1i:CB0i;
      const h2 CCr = q?CC1r:CC0r, CCi = q?CC1i:CC0i;
      const h2 CDr = q?CD1r:CD0r, CDi = q?CD1i:CD0i;
      const h2 vr = Vr[k0], vi = Vi[k0], ur = Vr[k1], ui = Vi[k1];
      h2 nvr = pkmul(CAr, vr); nvr = pkfma_n(CAi, vi, nvr);
      nvr = pkfma_s(CBr, ur, nvr); nvr = pkfma_ns(CBi, ui, nvr);
      h2 nvi = pkmul(CAr, vi); nvi = pkfma(CAi, vr, nvi);
      nvi = pkfma_s(CBr, ui, nvi); nvi = pkfma_s(CBi, ur, nvi);
      h2 nur = pkmul(CCr, ur); nur = pkfma_n(CCi, ui, nur);
      nur = pkfma_s(CDr, vr, nur); nur = pkfma_ns(CDi, vi, nur);
      h2 nui = pkmul(CCr, ui); nui = pkfma(CCi, ur, nui);
      nui = pkfma_s(CDr, vi, nui); nui = pkfma_s(CDi, vr, nui);
      Vr[k0] = nvr; Vi[k0] = nvi; Vr[k1] = nur; Vi[k1] = nui;
    }
  }
  #undef ER
  #undef EI
}

// Rot(phi,theta,omega) = RZ(omega) RY(theta) RZ(phi) -> 32 gates x 8 floats
__global__ void prep_gates(const float* __restrict__ qp, float* __restrict__ g) {
  int i = threadIdx.x;
  if (i >= 32) return;
  float phi = qp[i*3+0], th = qp[i*3+1], om = qp[i*3+2];
  float cth = cosf(0.5f*th), sth = sinf(0.5f*th);
  float a = 0.5f*(phi+om), d = 0.5f*(phi-om);
  float ca = cosf(a), sa = sinf(a), cd = cosf(d), sd = sinf(d);
  g[i*8+0] =  ca*cth; g[i*8+1] = -sa*cth;   // m00 = e^{-ia} c
  g[i*8+2] = -cd*sth; g[i*8+3] = -sd*sth;   // m01 = -e^{id} s
  g[i*8+4] =  cd*sth; g[i*8+5] = -sd*sth;   // m10 = e^{-id} s
  g[i*8+6] =  ca*cth; g[i*8+7] =  sa*cth;   // m11 = e^{ia} c
}

// ---------------------------------------------------------------------------
// PASS A: fixed global bits {15,14,13}=f, local {12..0}.
// L0 wires 3..15. Stages (lane bit chosen out of masks where possible):
//  S1: k->{9,10,11,12}, lane=8  (w3..w6 packed, w7 lane-only)
//  S2: k->{4,5,6,7},   lane=3  (w8..w11 packed, w12 lane-only)
//  S3: k->{0,1,2,11},  lane=12 (w13..w15 packed)
// ---------------------------------------------------------------------------
__global__ KATTR void passA(const float* __restrict__ x,
    unsigned* __restrict__ st, const float* __restrict__ g) {
  __shared__ unsigned L[8192];             // fp16-packed exchange buffer, 32 KB
  const int t = threadIdx.x;
  const int batch = blockIdx.x >> 3;
  const unsigned f = blockIdx.x & 7;
  const float* xb = x + ((size_t)batch << 16) + ((size_t)f << 13);

  h2 Vr[16], Vi[16];
  #pragma unroll
  for (int k = 0; k < 16; ++k) {
    Vr[k] = (h2){(_Float16)xb[((unsigned)k << 9) | (unsigned)t],
                 (_Float16)xb[((unsigned)k << 9) | 256u | (unsigned)t]};
    Vi[k] = (h2){(_Float16)0.f, (_Float16)0.f};
  }

  // S1: wires 3..7 (bits 12..8); roles in reg bits -> tp=0
  gateV<9,10,11,12,8, 0x1000u,0x1000u>(Vr, Vi, g, 3, 0u);
  gateV<9,10,11,12,8, 0x0800u,0x0800u>(Vr, Vi, g, 4, 0u);
  gateV<9,10,11,12,8, 0x0400u,0x0400u>(Vr, Vi, g, 5, 0u);
  gateV<9,10,11,12,8, 0x0200u,0x0200u>(Vr, Vi, g, 6, 0u);
  gateV<9,10,11,12,8, 0x0100u,0x0100u>(Vr, Vi, g, 7, 0u);   // lane-only

  // Exchange S1 -> S2 (identical LDS slots as R2/R6)
  {
    const unsigned wb = HASH((unsigned)t);
    #pragma unroll
    for (int k = 0; k < 16; ++k) {
      L[wb ^ HASH(((unsigned)k << 9))]        = AMPU(Vr[k], Vi[k], 0);
      L[wb ^ HASH(((unsigned)k << 9) | 256u)] = AMPU(Vr[k], Vi[k], 1);
    }
    __syncthreads();
    const unsigned rb = HASH((((unsigned)t & 0xF8u) << 5) | ((unsigned)t & 7u));
    #pragma unroll
    for (int k = 0; k < 16; ++k) {
      h2 h0 = H2(L[rb ^ HASH(((unsigned)k << 4))]);
      h2 h1 = H2(L[rb ^ HASH(((unsigned)k << 4) | 8u)]);
      Vr[k] = (h2){h0.x, h1.x};
      Vi[k] = (h2){h0.y, h1.y};
    }
  }

  // S2: wires 8..12 (bits 7..3)
  gateV<4,5,6,7,3, 0x0080u,0x0080u>(Vr, Vi, g,  8, 0u);
  gateV<4,5,6,7,3, 0x0040u,0x0040u>(Vr, Vi, g,  9, 0u);
  gateV<4,5,6,7,3, 0x0020u,0x0020u>(Vr, Vi, g, 10, 0u);
  gateV<4,5,6,7,3, 0x0010u,0x0010u>(Vr, Vi, g, 11, 0u);
  gateV<4,5,6,7,3, 0x0008u,0x0008u>(Vr, Vi, g, 12, 0u);     // lane-only

  // Exchange S2 -> S3
  __syncthreads();
  {
    const unsigned wb = HASH((((unsigned)t & 0xF8u) << 5) | ((unsigned)t & 7u));
    #pragma unroll
    for (int k = 0; k < 16; ++k) {
      L[wb ^ HASH(((unsigned)k << 4))]      = AMPU(Vr[k], Vi[k], 0);
      L[wb ^ HASH(((unsigned)k << 4) | 8u)] = AMPU(Vr[k], Vi[k], 1);
    }
    __syncthreads();
    const unsigned rb = HASH((unsigned)t << 3);
    #pragma unroll
    for (int k = 0; k < 16; ++k) {
      const unsigned kv = ((unsigned)k & 7u) | (((unsigned)k & 8u) << 8);
      h2 h0 = H2(L[rb ^ HASH(kv)]);
      h2 h1 = H2(L[rb ^ HASH(kv | 4096u)]);
      Vr[k] = (h2){h0.x, h1.x};
      Vi[k] = (h2){h0.y, h1.y};
    }
  }

  // S3: wires 13,14,15 (bits 2,1,0); lane=12 untouched by masks
  gateV<0,1,2,11,12, 0x0004u,0x0004u>(Vr, Vi, g, 13, 0u);
  gateV<0,1,2,11,12, 0x0002u,0x0002u>(Vr, Vi, g, 14, 0u);
  gateV<0,1,2,11,12, 0x0001u,0x0001u>(Vr, Vi, g, 15, 0u);

  // Store fp16: amp(k,l) at idx (l<<12)|((k>>3)<<11)|(t<<3)|(k&7)
  unsigned* outb = st + ((size_t)batch << 16) + ((size_t)f << 13);
  #pragma unroll
  for (int l = 0; l < 2; ++l) {
    #pragma unroll
    for (int kh = 0; kh < 2; ++kh) {
      uint4 q0, q1;
      q0.x = AMPU(Vr[kh*8+0], Vi[kh*8+0], l); q0.y = AMPU(Vr[kh*8+1], Vi[kh*8+1], l);
      q0.z = AMPU(Vr[kh*8+2], Vi[kh*8+2], l); q0.w = AMPU(Vr[kh*8+3], Vi[kh*8+3], l);
      q1.x = AMPU(Vr[kh*8+4], Vi[kh*8+4], l); q1.y = AMPU(Vr[kh*8+5], Vi[kh*8+5], l);
      q1.z = AMPU(Vr[kh*8+6], Vi[kh*8+6], l); q1.w = AMPU(Vr[kh*8+7], Vi[kh*8+7], l);
      const unsigned si = ((unsigned)l << 12) | ((unsigned)kh << 11) | ((unsigned)t << 3);
      *(uint4*)(outb + si) = q0;
      *(uint4*)(outb + si + 4) = q1;
    }
  }
}

// ---------------------------------------------------------------------------
// PASS B: fixed global bits {9,8,7}=c, local {15..10, 6..0} (packed: g>=10
// shift down 3). Stages:
//  SB1: k->{12,13,14,15}, lane=11 (w0,w1,w2, gi16..18 packed; gi19 cross)
//  SB2: k->{5,6,10,11},   lane=0  (gi20, gi25 packed)
//  SB3: k->{2,3,4,5},     lane=1  (gi26..28 packed; gi29 cross)
//  SB4: k->{0,1,14,15},   lane=13 (gi30, gi31 packed, per-lane roles)
// ---------------------------------------------------------------------------
__global__ KATTR void passB(unsigned* __restrict__ st,
    const float* __restrict__ g) {
  __shared__ unsigned L[8192];
  const int t = threadIdx.x;
  const int batch = blockIdx.x >> 3;
  const unsigned c = blockIdx.x & 7;
  unsigned* stb = st + ((size_t)batch << 16);

  // SB1 load: lbase: t[6:0]->g6..0, t7->g10, c->g9..7 ; k->g15..12, l->g11
  const unsigned lbase = ((unsigned)t & 127u) | (((unsigned)t & 128u) << 3) | (c << 7);
  h2 Vr[16], Vi[16];
  #pragma unroll
  for (int k = 0; k < 16; ++k) {
    h2 h0 = H2(stb[((unsigned)k << 12) | lbase]);
    h2 h1 = H2(stb[((unsigned)k << 12) | 2048u | lbase]);
    Vr[k] = (h2){h0.x, h1.x};
    Vi[k] = (h2){h0.y, h1.y};
  }

  const unsigned tp1 = lbase;
  gateV<12,13,14,15,11, 0x8000u,0x8000u>(Vr, Vi, g, 0, tp1);
  gateV<12,13,14,15,11, 0x4000u,0x4000u>(Vr, Vi, g, 1, tp1);
  gateV<12,13,14,15,11, 0x2000u,0x2000u>(Vr, Vi, g, 2, tp1);
  gateV<12,13,14,15,11, META.l1mask[0], META.l1role[0]>(Vr, Vi, g, 16, tp1);
  gateV<12,13,14,15,11, META.l1mask[1], META.l1role[1]>(Vr, Vi, g, 17, tp1);
  gateV<12,13,14,15,11, META.l1mask[2], META.l1role[2]>(Vr, Vi, g, 18, tp1);
  gateV<12,13,14,15,11, META.l1mask[3], META.l1role[3]>(Vr, Vi, g, 19, tp1); // cross

  // Exchange SB1 -> SB2 (packed space): identical slots as R2/R6
  {
    const unsigned wb = HASH((unsigned)t);
    #pragma unroll
    for (int k = 0; k < 16; ++k) {
      L[wb ^ HASH(((unsigned)k << 9))]        = AMPU(Vr[k], Vi[k], 0);
      L[wb ^ HASH(((unsigned)k << 9) | 256u)] = AMPU(Vr[k], Vi[k], 1);
    }
    __syncthreads();
    const unsigned rb = HASH((((unsigned)t & 0xF0u) << 5) | (((unsigned)t & 15u) << 1));
    #pragma unroll
    for (int k = 0; k < 16; ++k) {
      h2 h0 = H2(L[rb ^ HASH(((unsigned)k << 5))]);
      h2 h1 = H2(L[rb ^ HASH(((unsigned)k << 5) | 1u)]);
      Vr[k] = (h2){h0.x, h1.x};
      Vi[k] = (h2){h0.y, h1.y};
    }
  }

  // SB2: k->{5,6,10,11}, lane=0 ; tp: t7..t4->g15..12, t3..t0->g4..1
  const unsigned tp2 = (((unsigned)t & 0xF0u) << 8) | (((unsigned)t & 15u) << 1) | (c << 7);
  gateV<5,6,10,11,0, META.l1mask[4], META.l1role[4]>(Vr, Vi, g, 20, tp2);
  gateV<5,6,10,11,0, META.l1mask[9], META.l1role[9]>(Vr, Vi, g, 25, tp2);

  // Exchange SB2 -> SB3
  __syncthreads();
  {
    const unsigned wb = HASH((((unsigned)t & 0xF0u) << 5) | (((unsigned)t & 15u) << 1));
    #pragma unroll
    for (int k = 0; k < 16; ++k) {
      L[wb ^ HASH(((unsigned)k << 5))]      = AMPU(Vr[k], Vi[k], 0);
      L[wb ^ HASH(((unsigned)k << 5) | 1u)] = AMPU(Vr[k], Vi[k], 1);
    }
    __syncthreads();
    const unsigned rb = HASH((((unsigned)t & 0xFEu) << 5) | ((unsigned)t & 1u));
    #pragma unroll
    for (int k = 0; k < 16; ++k) {
      h2 h0 = H2(L[rb ^ HASH(((unsigned)k << 2))]);
      h2 h1 = H2(L[rb ^ HASH(((unsigned)k << 2) | 2u)]);
      Vr[k] = (h2){h0.x, h1.x};
      Vi[k] = (h2){h0.y, h1.y};
    }
  }

  // SB3: k->{2,3,4,5}, lane=1 ; tp: t7..t2->g15..g10, t1->g6, t0->g0
  const unsigned tp3 = (((unsigned)t & 0xFCu) << 8) | (((unsigned)t & 2u) << 5)
                     | ((unsigned)t & 1u) | (c << 7);
  gateV<2,3,4,5,1, META.l1mask[10], META.l1role[10]>(Vr, Vi, g, 26, tp3);
  gateV<2,3,4,5,1, META.l1mask[11], META.l1role[11]>(Vr, Vi, g, 27, tp3);
  gateV<2,3,4,5,1, META.l1mask[12], META.l1role[12]>(Vr, Vi, g, 28, tp3);
  gateV<2,3,4,5,1, META.l1mask[13], META.l1role[13]>(Vr, Vi, g, 29, tp3); // cross

  // Exchange SB3 -> SB4
  __syncthreads();
  {
    const unsigned wb = HASH((((unsigned)t & 0xFEu) << 5) | ((unsigned)t & 1u));
    #pragma unroll
    for (int k = 0; k < 16; ++k) {
      L[wb ^ HASH(((unsigned)k << 2))]      = AMPU(Vr[k], Vi[k], 0);
      L[wb ^ HASH(((unsigned)k << 2) | 2u)] = AMPU(Vr[k], Vi[k], 1);
    }
    __syncthreads();
    const unsigned rb = HASH((unsigned)t << 2);
    #pragma unroll
    for (int k = 0; k < 16; ++k) {
      const unsigned kv = ((unsigned)k & 3u) | (((unsigned)k & 12u) << 9);
      h2 h0 = H2(L[rb ^ HASH(kv)]);
      h2 h1 = H2(L[rb ^ HASH(kv | 1024u)]);
      Vr[k] = (h2){h0.x, h1.x};
      Vi[k] = (h2){h0.y, h1.y};
    }
  }

  // SB4: k->{0,1,14,15}, lane=13 ; tp: t7..t5->g12..g10, t4..t0->g6..g2
  const unsigned tp4 = (((unsigned)t & 0xE0u) << 5) | (((unsigned)t & 31u) << 2) | (c << 7);
  gateV<0,1,14,15,13, META.l1mask[14], META.l1role[14]>(Vr, Vi, g, 30, tp4);
  gateV<0,1,14,15,13, META.l1mask[15], META.l1role[15]>(Vr, Vi, g, 31, tp4);

  // Store: amp(k,l) at g = tp4 | (k&3) | (l<<13) | ((k>>2)<<14) -> dwordx4
  #pragma unroll
  for (int l = 0; l < 2; ++l) {
    #pragma unroll
    for (int kh = 0; kh < 4; ++kh) {
      uint4 q;
      q.x = AMPU(Vr[kh*4+0], Vi[kh*4+0], l); q.y = AMPU(Vr[kh*4+1], Vi[kh*4+1], l);
      q.z = AMPU(Vr[kh*4+2], Vi[kh*4+2], l); q.w = AMPU(Vr[kh*4+3], Vi[kh*4+3], l);
      *(uint4*)(stb + (tp4 | ((unsigned)l << 13) | ((unsigned)kh << 14))) = q;
    }
  }
}

// ---------------------------------------------------------------------------
// PASS C: fixed {15,14,13}=f, local {12..0}. k->{7,8,9,10}, lane=6:
// gi21..23 packed, gi24 cross. Then fused Z-expvals (f32 accumulate).
// ---------------------------------------------------------------------------
__global__ KATTR void passC(const unsigned* __restrict__ st,
    const float* __restrict__ g, float* __restrict__ partials) {
  __shared__ float R[4][17];
  const int t = threadIdx.x;
  const int batch = blockIdx.x >> 3;
  const unsigned f = blockIdx.x & 7;
  const unsigned* stb = st + ((size_t)batch << 16);

  // cbase: f->g15..13, t7,t6->g12,g11, t5..t0->g5..0 ; k->g10..7, l->g6
  const unsigned cbase = (f << 13) | (((unsigned)t & 192u) << 5) | ((unsigned)t & 63u);
  h2 Vr[16], Vi[16];
  #pragma unroll
  for (int k = 0; k < 16; ++k) {
    h2 h0 = H2(stb[cbase | ((unsigned)k << 7)]);
    h2 h1 = H2(stb[cbase | ((unsigned)k << 7) | 64u]);
    Vr[k] = (h2){h0.x, h1.x};
    Vi[k] = (h2){h0.y, h1.y};
  }

  gateV<7,8,9,10,6, META.l1mask[5], META.l1role[5]>(Vr, Vi, g, 21, cbase);
  gateV<7,8,9,10,6, META.l1mask[6], META.l1role[6]>(Vr, Vi, g, 22, cbase);
  gateV<7,8,9,10,6, META.l1mask[7], META.l1role[7]>(Vr, Vi, g, 23, cbase);
  gateV<7,8,9,10,6, META.l1mask[8], META.l1role[8]>(Vr, Vi, g, 24, cbase); // cross

  // Packed expvals (f32): reg contribution of (k,l) = (k<<7)|(l<<6)
  v2f sv2[16], tot2 = (v2f){0.f, 0.f};
  #pragma unroll
  for (int w = 0; w < 16; ++w) sv2[w] = (v2f){0.f, 0.f};
  const v2f lm = (v2f){1.f, -1.f};
  #pragma unroll
  for (int k = 0; k < 16; ++k) {
    v2f vr = {(float)Vr[k].x, (float)Vr[k].y};
    v2f vi = {(float)Vi[k].x, (float)Vi[k].y};
    v2f pr = vfma(vi, vi, vr*vr);
    tot2 = tot2 + pr;
    v2f prm = pr * lm;
    #pragma unroll
    for (int w = 0; w < 16; ++w) {
      const unsigned m = META.fin[w];
      const bool fl = ((m >> 6) & 1u) != 0;                               // folds
      const bool sk = (__builtin_popcount(m & ((unsigned)k << 7)) & 1) != 0; // folds
      const v2f term = fl ? prm : pr;
      sv2[w] = sk ? (sv2[w] - term) : (sv2[w] + term);
    }
  }
  float sv[16];
  #pragma unroll
  for (int w = 0; w < 16; ++w) sv[w] = sv2[w].x + sv2[w].y;
  float tot = tot2.x + tot2.y;
  #pragma unroll
  for (int w = 0; w < 16; ++w)
    if (__popc(META.fin[w] & cbase) & 1) sv[w] = -sv[w];   // thread-part sign

  #pragma unroll
  for (int off = 32; off; off >>= 1) {
    tot += __shfl_xor(tot, off, 64);
    #pragma unroll
    for (int w = 0; w < 16; ++w) sv[w] += __shfl_xor(sv[w], off, 64);
  }
  const int wave = t >> 6, lane = t & 63;
  if (lane == 0) {
    #pragma unroll
    for (int w = 0; w < 16; ++w) R[wave][w] = sv[w];
    R[wave][16] = tot;
  }
  __syncthreads();
  if (t < 17) {
    const float s2 = R[0][t] + R[1][t] + R[2][t] + R[3][t];
    partials[(size_t)blockIdx.x * 17 + t] = s2;
  }
}

__global__ __launch_bounds__(64) void head(const float* __restrict__ partials,
    const float* __restrict__ W, const float* __restrict__ bias,
    float* __restrict__ out) {
  const int b = blockIdx.x, tid = threadIdx.x;
  __shared__ float red[17];
  __shared__ float ev[16];
  if (tid < 17) {
    float s = 0.f;
    #pragma unroll
    for (int ch = 0; ch < 8; ++ch) s += partials[(size_t)((b << 3) + ch) * 17 + tid];
    red[tid] = s;
  }
  __syncthreads();
  if (tid < 16) ev[tid] = red[tid] / red[16];
  __syncthreads();
  if (tid < NCLS) {
    float o = bias[tid];
    #pragma unroll
    for (int w = 0; w < 16; ++w) o += ev[w] * W[tid*16 + w];
    out[b*NCLS + tid] = o;
  }
}

extern "C" void kernel_launch(void* const* d_in, const int* in_sizes, int n_in,
                              void* d_out, int out_size, void* d_ws, size_t ws_size,
                              hipStream_t stream) {
  const float* x  = (const float*)d_in[0];   // (256, 65536)
  const float* qp = (const float*)d_in[1];   // (2,16,3)
  const float* W  = (const float*)d_in[2];   // (10,16)
  const float* bv = (const float*)d_in[3];   // (10,)
  float* out = (float*)d_out;                // (256,10) fp32

  // ws: fp16 state (64 MB) | gates (1 KB) | partials (2048*17 floats)
  unsigned* st     = (unsigned*)d_ws;
  float*    gates  = (float*)((char*)d_ws + (size_t)BATCH * 65536 * 4);
  float*    parts  = (float*)((char*)gates + 1024);

  prep_gates<<<dim3(1), dim3(64), 0, stream>>>(qp, gates);
  passA<<<dim3(BATCH*8), dim3(256), 0, stream>>>(x, st, gates);
  passB<<<dim3(BATCH*8), dim3(256), 0, stream>>>(st, gates);
  passC<<<dim3(BATCH*8), dim3(256), 0, stream>>>(st, gates, parts);
  head<<<dim3(BATCH), dim3(64), 0, stream>>>(parts, W, bv, out);
}